// Round 9
// baseline (244.749 us; speedup 1.0000x reference)
//
#include <hip/hip_runtime.h>
#include <hip/hip_bf16.h>

typedef __attribute__((ext_vector_type(8))) short short8;
typedef __attribute__((ext_vector_type(4))) float f32x4;

#define NTOK   100000
#define H      150
#define NFR    10         // 16-col fragments (160 padded cols)
#define NKS    20         // K-steps of 32 (4 segs x 5)
#define BM     64         // token rows per block
#define LROW   168        // bf16 elems per LDS row (336B): conflict-free b128 reads
#define PROW   162        // fp32 elems per pre-row (648B): <=2-way on acc-layout writes
#define NSLOT  (BM * 75)  // 4800 float2 slots per 64x150 fp32 slab
#define OUTOFF (NTOK * H)

__device__ __forceinline__ unsigned short f2bf(float f) {
    unsigned int u = __builtin_bit_cast(unsigned int, f);
    u = (u + 0x7FFFu + ((u >> 16) & 1u)) >> 16;   // RNE
    return (unsigned short)u;
}

// ---------------------------------------------------------------------------
// Prepass: pack weights FRAGMENT-MAJOR so every B-frag load in the main
// kernel is 64 lanes x 16B = 1KB fully contiguous.
// wb[(((n*NKS + ks)*64 + lane)*8 + j] = W_seg[k2][col]
// ---------------------------------------------------------------------------
__global__ void prep_w(const float* __restrict__ w_in, const float* __restrict__ w_out,
                       const float* __restrict__ u_in, const float* __restrict__ u_out,
                       unsigned short* __restrict__ wb) {
    int idx = blockIdx.x * 256 + threadIdx.x;
    if (idx >= NFR * NKS * 64 * 8) return;       // 102400 elems
    int j    = idx & 7;
    int lane = (idx >> 3) & 63;
    int ks   = (idx >> 9) % NKS;
    int n    = idx / (512 * NKS);
    int seg  = ks / 5, s5 = ks % 5;
    int col  = n * 16 + (lane & 15);
    int k2   = s5 * 32 + (lane >> 4) * 8 + j;
    float v = 0.0f;
    if (col < H && k2 < H) {
        const float* W = (seg == 0) ? w_in : (seg == 1) ? w_out : (seg == 2) ? u_in : u_out;
        v = W[k2 * H + col];
    }
    wb[idx] = f2bf(v);
}

// ---------------------------------------------------------------------------
// Main fused kernel. Block = 64 token rows x 160 cols; 4 waves x 16 rows.
// GEMM phase (round-8 structure): double-buffered bf16 A-tiles in LDS; per
// segment {ds_write prefetched slab -> barrier -> issue next slab -> 5
// K-steps}; B frags stream 1KB-contiguous from L2-resident wb.
// NEW: LDS-transposed epilogue — pre dumped to LDS (aliasing the staging
// buffers), then lane-linear pointwise with fully-coalesced lc loads and
// hid/cell stores (512B/instr, full-line coverage, no write amplification).
// ---------------------------------------------------------------------------
__global__ __launch_bounds__(256, 3) void lstm_fused(
        const float* __restrict__ s_in, const float* __restrict__ s_out,
        const float* __restrict__ h_in, const float* __restrict__ h_out,
        const float* __restrict__ last_c, const unsigned short* __restrict__ wb,
        float* __restrict__ out) {
    __shared__ __align__(16) unsigned char lds_raw[2 * BM * LROW * 2];   // 43008 B
    typedef unsigned short XsT[BM][LROW];
    XsT* Xs = reinterpret_cast<XsT*>(lds_raw);              // Xs[2][64][168] bf16
    float (*preL)[PROW] = reinterpret_cast<float (*)[PROW]>(lds_raw);  // [64][162] f32, 41472 B

    const int t     = threadIdx.x;
    const int lane  = t & 63;
    const int wid   = t >> 6;
    const int lrow  = lane & 15;   // A row in frag / B+C col in frag
    const int lko   = lane >> 4;   // k-group 0..3 / C row-group
    const int r0blk = blockIdx.x * BM;

    const float* Xseg[4] = {s_in, s_out, h_in, h_out};
    const bool tail = (r0blk + BM > NTOK);   // last block only

    // zero k-pad elems [150,160) of every row in BOTH buffers
    for (int i = t; i < 2 * BM * 5; i += 256) {
        int b = i / (BM * 5);
        int r = (i / 5) % BM;
        int c = i % 5;
        *(unsigned int*)&Xs[b][r][150 + 2 * c] = 0u;
    }

    f32x4 acc[NFR];
#pragma unroll
    for (int n = 0; n < NFR; n++) acc[n] = (f32x4){0.f, 0.f, 0.f, 0.f};

    float2 pf[19];   // prefetch registers: 19 float2/thread covers 4800 slots

    auto issue = [&](int seg) {
        const float* __restrict__ Xp = Xseg[seg];
        if (!tail) {
            const float* __restrict__ Rp = Xp + (long)r0blk * H;
#pragma unroll
            for (int it = 0; it < 19; it++) {
                int s = t + it * 256;
                if (s < NSLOT) pf[it] = *(const float2*)&Rp[2 * s];   // 2s = row*150+2*c2
            }
        } else {
#pragma unroll
            for (int it = 0; it < 19; it++) {
                int s = t + it * 256;
                if (s < NSLOT) {
                    int row = s / 75, c2 = s - row * 75;
                    int gr = r0blk + row; if (gr > NTOK - 1) gr = NTOK - 1;
                    pf[it] = *(const float2*)&Xp[(long)gr * H + 2 * c2];
                }
            }
        }
    };

    issue(0);   // prologue

    for (int seg = 0; seg < 4; seg++) {
        // ---- convert + ds_write the slab prefetched for this segment ----
#pragma unroll
        for (int it = 0; it < 19; it++) {
            int s = t + it * 256;
            if (s < NSLOT) {
                int row = s / 75, c2 = s - row * 75;
                unsigned int p = (unsigned int)f2bf(pf[it].x)
                               | ((unsigned int)f2bf(pf[it].y) << 16);
                *(unsigned int*)&Xs[seg & 1][row][2 * c2] = p;
            }
        }
        __syncthreads();   // tile ready

        if (seg < 3) issue(seg + 1);   // next slab in flight under compute

        // ---- compute: 5 K-steps of {10 B-loads + 1 ds_read_b128 + 10 MFMA} ----
#pragma unroll
        for (int s5 = 0; s5 < 5; s5++) {
            const int ks = seg * 5 + s5;
            short8 bf[NFR];
#pragma unroll
            for (int n = 0; n < NFR; n++)
                bf[n] = *(const short8*)&wb[(((long)n * NKS + ks) * 64 + lane) * 8];
            short8 af = *(const short8*)&Xs[seg & 1][wid * 16 + lrow][s5 * 32 + lko * 8];
#pragma unroll
            for (int n = 0; n < NFR; n++)
                acc[n] = __builtin_amdgcn_mfma_f32_16x16x32_bf16(af, bf[n], acc[n], 0, 0, 0);
        }
    }

    // ---- LDS-transposed epilogue ----
    __syncthreads();   // all Xs reads done; safe to overwrite with preL
#pragma unroll
    for (int n = 0; n < NFR; n++)
#pragma unroll
        for (int r = 0; r < 4; r++)
            preL[wid * 16 + lko * 4 + r][n * 16 + lrow] = acc[n][r];
    __syncthreads();   // pre tile ready

    const float* __restrict__ lcp  = last_c + (long)r0blk * H;
    float* __restrict__ hidp = out + (long)r0blk * H;
    float* __restrict__ celp = out + OUTOFF + (long)r0blk * H;

#pragma unroll
    for (int it = 0; it < 19; it++) {
        int s = t + it * 256;
        if (s < NSLOT) {
            int row = s / 75, c2 = s - row * 75;
            bool ok = !tail || (r0blk + row < NTOK);
            if (ok) {
                float2 pre2 = *(const float2*)&preL[row][2 * c2];
                float2 lc2  = *(const float2*)&lcp[2 * s];
                float2 h2, cl2;
                {
                    float e  = __expf(-pre2.x);
                    float g  = __builtin_amdgcn_rcpf(1.f + e);
                    float cl = g * lc2.x + g * g;
                    float e2 = __expf(-2.f * cl);
                    float th = (1.f - e2) * __builtin_amdgcn_rcpf(1.f + e2);
                    h2.x = g * th; cl2.x = cl;
                }
                {
                    float e  = __expf(-pre2.y);
                    float g  = __builtin_amdgcn_rcpf(1.f + e);
                    float cl = g * lc2.y + g * g;
                    float e2 = __expf(-2.f * cl);
                    float th = (1.f - e2) * __builtin_amdgcn_rcpf(1.f + e2);
                    h2.y = g * th; cl2.y = cl;
                }
                *(float2*)&hidp[2 * s] = h2;
                *(float2*)&celp[2 * s] = cl2;
            }
        }
    }
}

extern "C" void kernel_launch(void* const* d_in, const int* in_sizes, int n_in,
                              void* d_out, int out_size, void* d_ws, size_t ws_size,
                              hipStream_t stream) {
    const float* s_in   = (const float*)d_in[0];
    const float* s_out  = (const float*)d_in[1];
    const float* h_in   = (const float*)d_in[2];
    const float* h_out  = (const float*)d_in[3];
    const float* last_c = (const float*)d_in[4];
    const float* w_in   = (const float*)d_in[5];
    const float* w_out  = (const float*)d_in[6];
    const float* u_in   = (const float*)d_in[7];
    const float* u_out  = (const float*)d_in[8];

    unsigned short* wb = (unsigned short*)d_ws;   // 102400*2 = 204800 B
    float* out = (float*)d_out;

    prep_w<<<(NFR * NKS * 64 * 8 + 255) / 256, 256, 0, stream>>>(w_in, w_out, u_in, u_out, wb);

    const int nblocks = (NTOK + BM - 1) / BM;  // 1563 blocks, 4 waves, 16 rows/wave
    lstm_fused<<<nblocks, 256, 0, stream>>>(s_in, s_out, h_in, h_out, last_c, wb, out);
}

// Round 10
// 233.741 us; speedup vs baseline: 1.0471x; 1.0471x over previous
//
#include <hip/hip_runtime.h>
#include <hip/hip_bf16.h>

typedef __attribute__((ext_vector_type(8))) short short8;
typedef __attribute__((ext_vector_type(4))) float f32x4;

#define NTOK   100000
#define H      150
#define NFR    10         // 16-col fragments (160 padded cols)
#define NKS    20         // K-steps of 32 (4 segs x 5)
#define BM     32         // token rows per block (100000 = 32*3125, no tail)
#define LROW   168        // bf16 elems per LDS row (336B): conflict-free b128 reads
#define NSLOT  (BM * 75)  // 2400 float2 slots per 32x150 fp32 slab
#define OUTOFF (NTOK * H)

__device__ __forceinline__ unsigned short f2bf(float f) {
    unsigned int u = __builtin_bit_cast(unsigned int, f);
    u = (u + 0x7FFFu + ((u >> 16) & 1u)) >> 16;   // RNE
    return (unsigned short)u;
}

// ---------------------------------------------------------------------------
// Prepass: pack weights FRAGMENT-MAJOR so every B-frag load in the main
// kernel is 64 lanes x 16B = 1KB fully contiguous.
// wb[(((n*NKS + ks)*64 + lane)*8 + j] = W_seg[k2][col]
//   seg = ks/5, s5 = ks%5, col = n*16 + (lane&15), k2 = s5*32 + (lane>>4)*8 + j
// ---------------------------------------------------------------------------
__global__ void prep_w(const float* __restrict__ w_in, const float* __restrict__ w_out,
                       const float* __restrict__ u_in, const float* __restrict__ u_out,
                       unsigned short* __restrict__ wb) {
    int idx = blockIdx.x * 256 + threadIdx.x;
    if (idx >= NFR * NKS * 64 * 8) return;       // 102400 elems
    int j    = idx & 7;
    int lane = (idx >> 3) & 63;
    int ks   = (idx >> 9) % NKS;
    int n    = idx / (512 * NKS);
    int seg  = ks / 5, s5 = ks % 5;
    int col  = n * 16 + (lane & 15);
    int k2   = s5 * 32 + (lane >> 4) * 8 + j;
    float v = 0.0f;
    if (col < H && k2 < H) {
        const float* W = (seg == 0) ? w_in : (seg == 1) ? w_out : (seg == 2) ? u_in : u_out;
        v = W[k2 * H + col];
    }
    wb[idx] = f2bf(v);
}

// ---------------------------------------------------------------------------
// Main fused kernel (round-8 structure, BM 64->32 for 7 blocks/CU).
// Block = 32 token rows x 160 cols; 2 waves, each wave 16 rows x all cols.
// Double-buffered bf16 A-tiles in LDS (21.5KB); per segment {ds_write
// prefetched slab -> barrier -> issue next slab -> 5 K-steps}. One barrier
// per segment. B frags stream 1KB-contiguous from L2-resident wb.
// ---------------------------------------------------------------------------
__global__ __launch_bounds__(128, 4) void lstm_fused(
        const float* __restrict__ s_in, const float* __restrict__ s_out,
        const float* __restrict__ h_in, const float* __restrict__ h_out,
        const float* __restrict__ last_c, const unsigned short* __restrict__ wb,
        float* __restrict__ out) {
    __shared__ unsigned short Xs[2][BM][LROW];   // 21504 B -> 7 blocks/CU

    const int t     = threadIdx.x;
    const int lane  = t & 63;
    const int wid   = t >> 6;      // 0..1
    const int lrow  = lane & 15;   // A row in frag / B+C col in frag
    const int lko   = lane >> 4;   // k-group 0..3 / C row-group
    const int r0blk = blockIdx.x * BM;
    const int r0w   = r0blk + wid * 16;

    const float* Xseg[4] = {s_in, s_out, h_in, h_out};

    // zero k-pad elems [150,160) of every row in BOTH buffers
    for (int i = t; i < 2 * BM * 5; i += 128) {
        int b = i / (BM * 5);
        int r = (i / 5) % BM;
        int c = i % 5;
        *(unsigned int*)&Xs[b][r][150 + 2 * c] = 0u;
    }

    f32x4 acc[NFR];
#pragma unroll
    for (int n = 0; n < NFR; n++) acc[n] = (f32x4){0.f, 0.f, 0.f, 0.f};

    float2 pf[19];   // prefetch registers: 19 float2/thread covers 2400 slots

    // issue segment's global loads (lane-linear over the contiguous 19.2KB slab)
    auto issue = [&](int seg) {
        const float* __restrict__ Rp = Xseg[seg] + (long)r0blk * H;
#pragma unroll
        for (int it = 0; it < 19; it++) {
            int s = t + it * 128;
            if (s < NSLOT) pf[it] = *(const float2*)&Rp[2 * s];   // 2s = row*150+2*c2
        }
    };

    issue(0);   // prologue

    for (int seg = 0; seg < 4; seg++) {
        // ---- convert + ds_write the slab prefetched for this segment ----
#pragma unroll
        for (int it = 0; it < 19; it++) {
            int s = t + it * 128;
            if (s < NSLOT) {
                int row = s / 75, c2 = s - row * 75;
                unsigned int p = (unsigned int)f2bf(pf[it].x)
                               | ((unsigned int)f2bf(pf[it].y) << 16);
                *(unsigned int*)&Xs[seg & 1][row][2 * c2] = p;
            }
        }
        __syncthreads();   // tile ready

        if (seg < 3) issue(seg + 1);   // next slab in flight under compute

        // ---- compute: 5 K-steps of {10 B-loads + 1 ds_read_b128 + 10 MFMA} ----
#pragma unroll
        for (int s5 = 0; s5 < 5; s5++) {
            const int ks = seg * 5 + s5;
            short8 bf[NFR];
#pragma unroll
            for (int n = 0; n < NFR; n++)
                bf[n] = *(const short8*)&wb[(((long)n * NKS + ks) * 64 + lane) * 8];
            short8 af = *(const short8*)&Xs[seg & 1][wid * 16 + lrow][s5 * 32 + lko * 8];
#pragma unroll
            for (int n = 0; n < NFR; n++)
                acc[n] = __builtin_amdgcn_mfma_f32_16x16x32_bf16(af, bf[n], acc[n], 0, 0, 0);
        }
    }

    // ---- fused epilogue (round-8 style): g=sigmoid(pre); cell=g*lc+g*g; hid=g*tanh(cell)
#pragma unroll
    for (int r = 0; r < 4; r++) {
        const int row = r0w + lko * 4 + r;          // always < NTOK (no tail)
        const long rb = (long)row * H;
#pragma unroll
        for (int n = 0; n < NFR; n++) {
            const int col = n * 16 + lrow;
            if (col >= H) continue;
            float pre = acc[n][r];
            float e   = __expf(-pre);
            float g   = __builtin_amdgcn_rcpf(1.f + e);
            float lc  = last_c[rb + col];
            float cell = g * lc + g * g;
            float e2  = __expf(-2.f * cell);
            float th  = (1.f - e2) * __builtin_amdgcn_rcpf(1.f + e2);
            out[rb + col]          = g * th;
            out[OUTOFF + rb + col] = cell;
        }
    }
}

extern "C" void kernel_launch(void* const* d_in, const int* in_sizes, int n_in,
                              void* d_out, int out_size, void* d_ws, size_t ws_size,
                              hipStream_t stream) {
    const float* s_in   = (const float*)d_in[0];
    const float* s_out  = (const float*)d_in[1];
    const float* h_in   = (const float*)d_in[2];
    const float* h_out  = (const float*)d_in[3];
    const float* last_c = (const float*)d_in[4];
    const float* w_in   = (const float*)d_in[5];
    const float* w_out  = (const float*)d_in[6];
    const float* u_in   = (const float*)d_in[7];
    const float* u_out  = (const float*)d_in[8];

    unsigned short* wb = (unsigned short*)d_ws;   // 102400*2 = 204800 B
    float* out = (float*)d_out;

    prep_w<<<(NFR * NKS * 64 * 8 + 255) / 256, 256, 0, stream>>>(w_in, w_out, u_in, u_out, wb);

    const int nblocks = NTOK / BM;  // 3125 blocks, 2 waves, 16 rows/wave
    lstm_fused<<<nblocks, 128, 0, stream>>>(s_in, s_out, h_in, h_out, last_c, wb, out);
}

// Round 11
// 135.526 us; speedup vs baseline: 1.8059x; 1.7247x over previous
//
#include <hip/hip_runtime.h>
#include <hip/hip_bf16.h>

typedef __attribute__((ext_vector_type(8))) short short8;
typedef __attribute__((ext_vector_type(4))) float f32x4;

#define NTOK   100000
#define H      150
#define NFR    10          // 16-col fragments (160 padded cols)
#define NKS    20          // K-steps of 32 (4 segs x 5)
#define BM     64          // token rows per block
#define SLAB   38400       // BM*H*4 bytes per fp32 slab
#define NCHUNK 38          // ceil(SLAB/1024) 1KB DMA chunks
#define BUFB   (NCHUNK*1024)  // 38912 B per LDS buffer (incl. pad)
#define OUTOFF (NTOK * H)
#define XLIM   ((long)NTOK * H * 4 - 16)   // last valid 16B-aligned src offset

__device__ __forceinline__ unsigned short f2bf(float f) {
    unsigned int u = __builtin_bit_cast(unsigned int, f);
    u = (u + 0x7FFFu + ((u >> 16) & 1u)) >> 16;   // RNE
    return (unsigned short)u;
}

// ---------------------------------------------------------------------------
// Prepass: pack weights FRAGMENT-MAJOR so every B-frag load in the main
// kernel is 64 lanes x 16B = 1KB fully contiguous.
// wb[(((n*NKS + ks)*64 + lane)*8 + j] = W_seg[k2][col]
//   seg = ks/5, s5 = ks%5, col = n*16 + (lane&15), k2 = s5*32 + (lane>>4)*8 + j
// ---------------------------------------------------------------------------
__global__ void prep_w(const float* __restrict__ w_in, const float* __restrict__ w_out,
                       const float* __restrict__ u_in, const float* __restrict__ u_out,
                       unsigned short* __restrict__ wb) {
    int idx = blockIdx.x * 256 + threadIdx.x;
    if (idx >= NFR * NKS * 64 * 8) return;       // 102400 elems
    int j    = idx & 7;
    int lane = (idx >> 3) & 63;
    int ks   = (idx >> 9) % NKS;
    int n    = idx / (512 * NKS);
    int seg  = ks / 5, s5 = ks % 5;
    int col  = n * 16 + (lane & 15);
    int k2   = s5 * 32 + (lane >> 4) * 8 + j;
    float v = 0.0f;
    if (col < H && k2 < H) {
        const float* W = (seg == 0) ? w_in : (seg == 1) ? w_out : (seg == 2) ? u_in : u_out;
        v = W[k2 * H + col];
    }
    wb[idx] = f2bf(v);
}

// ---------------------------------------------------------------------------
// Main fused kernel. Block = 64 token rows x 160 cols; 4 waves x 16 rows.
// X staged fp32 via global_load_lds width=16 (zero-VGPR DMA, linear LDS dest
// matching the contiguous 38.4KB slab); double-buffered; per segment
// {stage(seg+1) -> compute 5 K-steps (A: ds_read fp32 + cvt; B: 1KB-contig
// L2 loads, batch-issued with the freed VGPRs) -> barrier}.
// ---------------------------------------------------------------------------
__global__ __launch_bounds__(256, 2) void lstm_fused(
        const float* __restrict__ s_in, const float* __restrict__ s_out,
        const float* __restrict__ h_in, const float* __restrict__ h_out,
        const float* __restrict__ last_c, const unsigned short* __restrict__ wb,
        float* __restrict__ out) {
    __shared__ __align__(16) unsigned char Xr[2][BUFB];   // 77824 B -> 2 blocks/CU

    const int t     = threadIdx.x;
    const int lane  = t & 63;
    const int wid   = t >> 6;      // 0..3
    const int lrow  = lane & 15;   // A row in frag / B+C col in frag
    const int lko   = lane >> 4;   // k-group 0..3 / C row-group
    const int r0blk = blockIdx.x * BM;
    const int r0w   = r0blk + wid * 16;

    const float* Xseg[4] = {s_in, s_out, h_in, h_out};

    f32x4 acc[NFR];
#pragma unroll
    for (int n = 0; n < NFR; n++) acc[n] = (f32x4){0.f, 0.f, 0.f, 0.f};

    // ---- DMA stage: wave-striped 1KB chunks, zero VGPR cost ----
    auto stage = [&](int seg, int buf) {
        const char* base = (const char*)Xseg[seg];
        const long sofs = (long)r0blk * (H * 4);
        for (int c = wid; c < NCHUNK; c += 4) {
            long go = sofs + c * 1024 + lane * 16;
            if (go > XLIM) go = XLIM;              // tail-block clamp (valid floats)
            const void* gp = base + go;
            void* lp = &Xr[buf][c * 1024];         // wave-uniform dest
            __builtin_amdgcn_global_load_lds(
                (const __attribute__((address_space(1))) void*)gp,
                (__attribute__((address_space(3))) void*)lp, 16, 0, 0);
        }
    };

    stage(0, 0);
    __syncthreads();   // drains stage-0 DMA (vmcnt) + sync

    for (int seg = 0; seg < 4; seg++) {
        if (seg < 3) stage(seg + 1, (seg + 1) & 1);   // in flight under compute

        const float* Xf = (const float*)&Xr[seg & 1][0];   // [64][150] fp32
        const int row = wid * 16 + lrow;

        // ---- compute: 5 K-steps of {10 batched B-loads + A cvt + 10 MFMA} ----
#pragma unroll
        for (int s5 = 0; s5 < 5; s5++) {
            const int ks = seg * 5 + s5;
            short8 bf[NFR];
#pragma unroll
            for (int n = 0; n < NFR; n++)
                bf[n] = *(const short8*)&wb[(((long)n * NKS + ks) * 64 + lane) * 8];

            const int k0 = s5 * 32 + lko * 8;
            const float* rp = Xf + row * H + k0;   // 8B-aligned
            float xv[8];
#pragma unroll
            for (int j = 0; j < 8; j += 2) {
                float2 v = *(const float2*)&rp[j];
                xv[j] = v.x; xv[j + 1] = v.y;
            }
            if (s5 == 4) {                          // k0 = 128+lko*8; mask k >= 150
#pragma unroll
                for (int j = 0; j < 8; j++)
                    xv[j] = (k0 + j < H) ? xv[j] : 0.f;
            }
            short8 af;
#pragma unroll
            for (int j = 0; j < 8; j++) af[j] = (short)f2bf(xv[j]);

#pragma unroll
            for (int n = 0; n < NFR; n++)
                acc[n] = __builtin_amdgcn_mfma_f32_16x16x32_bf16(af, bf[n], acc[n], 0, 0, 0);
        }
        __syncthreads();   // next tile's DMA done; buffer reuse safe
    }

    // ---- fused epilogue (r8-verbatim): g=sigmoid(pre); cell=g*lc+g*g; hid=g*tanh(cell)
#pragma unroll
    for (int r = 0; r < 4; r++) {
        const int row = r0w + lko * 4 + r;
        if (row >= NTOK) continue;
        const long rb = (long)row * H;
#pragma unroll
        for (int n = 0; n < NFR; n++) {
            const int col = n * 16 + lrow;
            if (col >= H) continue;
            float pre = acc[n][r];
            float e   = __expf(-pre);
            float g   = __builtin_amdgcn_rcpf(1.f + e);
            float lc  = last_c[rb + col];
            float cell = g * lc + g * g;
            float e2  = __expf(-2.f * cell);
            float th  = (1.f - e2) * __builtin_amdgcn_rcpf(1.f + e2);
            out[rb + col]          = g * th;
            out[OUTOFF + rb + col] = cell;
        }
    }
}

extern "C" void kernel_launch(void* const* d_in, const int* in_sizes, int n_in,
                              void* d_out, int out_size, void* d_ws, size_t ws_size,
                              hipStream_t stream) {
    const float* s_in   = (const float*)d_in[0];
    const float* s_out  = (const float*)d_in[1];
    const float* h_in   = (const float*)d_in[2];
    const float* h_out  = (const float*)d_in[3];
    const float* last_c = (const float*)d_in[4];
    const float* w_in   = (const float*)d_in[5];
    const float* w_out  = (const float*)d_in[6];
    const float* u_in   = (const float*)d_in[7];
    const float* u_out  = (const float*)d_in[8];

    unsigned short* wb = (unsigned short*)d_ws;   // 102400*2 = 204800 B
    float* out = (float*)d_out;

    prep_w<<<(NFR * NKS * 64 * 8 + 255) / 256, 256, 0, stream>>>(w_in, w_out, u_in, u_out, wb);

    const int nblocks = (NTOK + BM - 1) / BM;  // 1563 blocks, 4 waves, 16 rows/wave
    lstm_fused<<<nblocks, 256, 0, stream>>>(s_in, s_out, h_in, h_out, last_c, wb, out);
}